// Round 22
// baseline (796.987 us; speedup 1.0000x reference)
//
#include <hip/hip_runtime.h>
#include <hip/hip_bf16.h>
#include <stdint.h>

// Problem constants: B=4, S=2048, IN=4096, OUT=11008
#define M_DIM 8192   // B*S
#define N_DIM 11008  // OUT
#define K_DIM 4096   // IN
#define NGROUP 32    // K_DIM/128

#define BM 256
#define BN 256
#define BK 128
#define NT (K_DIM / BK)  // 32 K-tiles

typedef __attribute__((ext_vector_type(4))) int i32x4;
typedef __attribute__((ext_vector_type(4))) float f32x4;

static_assert(M_DIM % BM == 0 && N_DIM % BN == 0 && K_DIM % BK == 0, "tiling");

// ---------- fused prepass: blocks [0,8192) quantize x rows; [8192,10944) quantize W rows ----------
__global__ __launch_bounds__(256) void quant_fused_kernel(const float* __restrict__ x,
                                                          int8_t* __restrict__ xq,
                                                          float* __restrict__ sx,
                                                          const int* __restrict__ qw,
                                                          const float* __restrict__ sc,
                                                          const float* __restrict__ zp,
                                                          int8_t* __restrict__ wq,
                                                          float* __restrict__ swc) {
  __shared__ float red[4];
  __shared__ float sfin;
  const int tid = threadIdx.x;

  if (blockIdx.x < M_DIM) {
    // ---- x row -> i8, per-row scale ----
    const int m = blockIdx.x;
    const float* xr = x + (size_t)m * K_DIM;
    float4 v[4];
    float mx = 0.f;
#pragma unroll
    for (int i = 0; i < 4; ++i) {
      v[i] = *(const float4*)(xr + tid * 16 + i * 4);
      mx = fmaxf(mx, fmaxf(fmaxf(fabsf(v[i].x), fabsf(v[i].y)),
                           fmaxf(fabsf(v[i].z), fabsf(v[i].w))));
    }
#pragma unroll
    for (int off = 32; off; off >>= 1) mx = fmaxf(mx, __shfl_xor(mx, off));
    if ((tid & 63) == 0) red[tid >> 6] = mx;
    __syncthreads();
    if (tid == 0) {
      float t = fmaxf(fmaxf(red[0], red[1]), fmaxf(red[2], red[3]));
      t = fmaxf(t, 1e-20f);
      sfin = t;
      sx[m] = t * (1.0f / 127.0f);
    }
    __syncthreads();
    const float inv = 127.0f / sfin;
    int o[4];
#pragma unroll
    for (int i = 0; i < 4; ++i) {
      int q0 = (int)rintf(v[i].x * inv), q1 = (int)rintf(v[i].y * inv);
      int q2 = (int)rintf(v[i].z * inv), q3 = (int)rintf(v[i].w * inv);
      o[i] = (q0 & 0xff) | ((q1 & 0xff) << 8) | ((q2 & 0xff) << 16) | (q3 << 24);
    }
    *(int4*)(xq + (size_t)m * K_DIM + tid * 16) = make_int4(o[0], o[1], o[2], o[3]);
  } else {
    // ---- W row -> i8, per-output-row scale; single global read (row held in regs) ----
    const int o = (blockIdx.x - M_DIM) * 4 + (tid >> 6);
    const int lane = tid & 63;
    const int* row = qw + (size_t)o * 2048;
    const float* srow = sc + o * NGROUP;
    const float* zrow = zp + o * NGROUP;
    int q[32];
    float mx = 0.f;
#pragma unroll
    for (int i = 0; i < 32; ++i) {
      q[i] = row[i * 64 + lane];
      float s = srow[i], z = zrow[i];
      float lo = ((float)(q[i] & 15) - z) * s;
      float hi = ((float)((q[i] >> 4) & 15) - z) * s;
      mx = fmaxf(mx, fmaxf(fabsf(lo), fabsf(hi)));
    }
#pragma unroll
    for (int off = 32; off; off >>= 1) mx = fmaxf(mx, __shfl_xor(mx, off));
    mx = fmaxf(mx, 1e-20f);
    if (lane == 0) swc[o] = mx * (1.0f / 127.0f);
    const float inv = 127.0f / mx;
    short* out = (short*)(wq + (size_t)o * K_DIM);
#pragma unroll
    for (int i = 0; i < 32; ++i) {
      float s = srow[i], z = zrow[i];
      int rlo = (int)rintf(((float)(q[i] & 15) - z) * s * inv);
      int rhi = (int)rintf(((float)((q[i] >> 4) & 15) - z) * s * inv);
      out[i * 64 + lane] = (short)((rlo & 0xff) | (rhi << 8));
    }
  }
}

// ---------- 256x256 i8 GEMM, R9 schedule, BK=128, 2D XCD supertile,
//            NT full-line epilogue via per-wave LDS transpose ----------
__device__ __forceinline__ void gload_lds16(const void* g, void* l) {
  __builtin_amdgcn_global_load_lds((__attribute__((address_space(1))) void*)g,
                                   (__attribute__((address_space(3))) void*)l,
                                   16, 0, 0);
}

// Stage one k-half panel [256 rows][64 i8] (16KB), 2 gload_lds per thread.
__device__ __forceinline__ void stage2(const int8_t* s0, const int8_t* s1,
                                       int8_t* panel, int wave, int koff) {
  gload_lds16(s0 + koff, panel + wave * 1024);
  gload_lds16(s1 + koff, panel + 8192 + wave * 1024);
}

#define VMC(N) asm volatile("s_waitcnt vmcnt(" #N ")" ::: "memory")
#define PUB(N) { VMC(N); __builtin_amdgcn_s_barrier(); }

// Fragment reads (i8: 16B = 16 elems along K per lane).
#define RD_AV(DST, P, MH)                                                    \
  _Pragma("unroll") for (int m_ = 0; m_ < 4; ++m_)                           \
    DST[m_] = *(const i32x4*)((P) + abase + ((MH)*4 + m_) * 1024);
#define RD_BV(DST, P)                                                        \
  _Pragma("unroll") for (int n_ = 0; n_ < 4; ++n_)                           \
    DST[n_] = *(const i32x4*)((P) + bbase + n_ * 1024);

#define MFMA_BLK(MH, AV, BV)                                                 \
  {                                                                          \
    __builtin_amdgcn_s_setprio(1);                                           \
    _Pragma("unroll") for (int m_ = 0; m_ < 4; ++m_)                         \
      _Pragma("unroll") for (int n_ = 0; n_ < 4; ++n_)                       \
        acc[(MH)*4 + m_][n_] = __builtin_amdgcn_mfma_i32_16x16x64_i8(        \
            AV[m_], BV[n_], acc[(MH)*4 + m_][n_], 0, 0, 0);                  \
    __builtin_amdgcn_s_setprio(0);                                           \
  }

__global__ __launch_bounds__(512, 2) void gemm_i8_kernel(const int8_t* __restrict__ A,
                                                         const int8_t* __restrict__ B,
                                                         const float* __restrict__ sx,
                                                         const float* __restrict__ swc,
                                                         float* __restrict__ C) {
  extern __shared__ int8_t lds[];
  int8_t* As = lds;            // [2 buf][2 kh][256*64]  = 64KB
  int8_t* Bs = lds + 65536;    // same                   = 64KB

  const int tid  = threadIdx.x;
  const int wave = tid >> 6;
  const int lane = tid & 63;
  const int wm = wave >> 2;   // 0..1 -> 128-row slab
  const int wn = wave & 3;    // 0..3 -> 64-col slab
  const int fr = lane & 15;
  const int cp = (lane >> 4) ^ ((fr >> 1) & 3);  // swizzled physical 16B-block

  // 2D XCD supertile (bijective, R20-verified: FETCH 759->278 MB)
  const int wg  = blockIdx.x;
  const int xcd = wg & 7;
  const int j   = wg >> 3;          // 0..171
  const int bm  = xcd * 4 + (j & 3);
  const int bn  = j >> 2;           // 0..42
  const size_t row0 = (size_t)bm * BM;
  const size_t col0 = (size_t)bn * BN;

  const int8_t* Ab = A + row0 * K_DIM;
  const int8_t* Bb = B + col0 * K_DIM;

  // per-lane staging sources (swizzle baked into global col, rule #21)
  const int cl = (tid & 3) ^ ((tid >> 3) & 3);
  const int r0 = tid >> 2;
  const int8_t* asrc0 = Ab + (size_t)r0 * K_DIM + cl * 16;
  const int8_t* asrc1 = Ab + (size_t)(r0 + 128) * K_DIM + cl * 16;
  const int8_t* bsrc0 = Bb + (size_t)r0 * K_DIM + cl * 16;
  const int8_t* bsrc1 = Bb + (size_t)(r0 + 128) * K_DIM + cl * 16;

  // fragment LDS byte offsets (panel-local); frag mf at abase + mf*1024
  const int abase = (wm * 128 + fr) * 64 + cp * 16;
  const int bbase = (wn * 64 + fr) * 64 + cp * 16;

  i32x4 acc[8][4];
#pragma unroll
  for (int i = 0; i < 8; ++i)
#pragma unroll
    for (int j2 = 0; j2 < 4; ++j2) acc[i][j2] = (i32x4){0, 0, 0, 0};

  i32x4 av0[4], av1[4], bv0[4], bv1[4];

  // ---- prologue: stage tile 0 fully; pre-read P1's fragments ----
  stage2(asrc0, asrc1, As + 0 * 16384, wave, 0);
  stage2(bsrc0, bsrc1, Bs + 0 * 16384, wave, 0);
  stage2(asrc0, asrc1, As + 1 * 16384, wave, 64);
  stage2(bsrc0, bsrc1, Bs + 1 * 16384, wave, 64);
  VMC(4);
  __builtin_amdgcn_s_barrier();
  RD_AV(av0, As + 0 * 16384, 0);
  RD_BV(bv0, Bs + 0 * 16384);

  // ---- main loop: R9 schedule, 4 phases/K-tile, publishes at P1/P3 ----
  for (int T = 0; T < NT - 1; ++T) {
    const int buf = T & 1, nb = buf ^ 1;
    int8_t* A0 = As + (buf * 2 + 0) * 16384;
    int8_t* A1 = As + (buf * 2 + 1) * 16384;
    int8_t* B1 = Bs + (buf * 2 + 1) * 16384;
    int8_t* nA0 = As + (nb * 2 + 0) * 16384;
    int8_t* nA1 = As + (nb * 2 + 1) * 16384;
    int8_t* nB0 = Bs + (nb * 2 + 0) * 16384;
    int8_t* nB1 = Bs + (nb * 2 + 1) * 16384;
    const int k0 = (T + 1) * 128;     // prefetch col offset (i8 elems)

    // P1: MFMA(kh0,mh0); pre-read av1<-A0.mh1; stage nA0; PUBLISH kh1
    RD_AV(av1, A0, 1);
    stage2(asrc0, asrc1, nA0, wave, k0);
    MFMA_BLK(0, av0, bv0);
    PUB(2);
    // P2: MFMA(kh0,mh1); pre-read av0<-A1.mh0, bv1<-B1; stage nB0
    RD_AV(av0, A1, 0);
    RD_BV(bv1, B1);
    stage2(bsrc0, bsrc1, nB0, wave, k0);
    MFMA_BLK(1, av1, bv0);
    // P3: MFMA(kh1,mh0); pre-read av1<-A1.mh1; stage nA1; PUBLISH next kh0
    RD_AV(av1, A1, 1);
    stage2(asrc0, asrc1, nA1, wave, k0 + 64);
    MFMA_BLK(0, av0, bv1);
    PUB(2);
    // P4: MFMA(kh1,mh1); pre-read next P1 frags from nA0,nB0; stage nB1
    RD_AV(av0, nA0, 0);
    RD_BV(bv0, nB0);
    stage2(bsrc0, bsrc1, nB1, wave, k0 + 64);
    MFMA_BLK(1, av1, bv1);
  }
  // ---- last tile: no staging; drain remaining at P1-end ----
  {
    const int buf = (NT - 1) & 1;
    int8_t* A0 = As + (buf * 2 + 0) * 16384;
    int8_t* A1 = As + (buf * 2 + 1) * 16384;
    int8_t* B1 = Bs + (buf * 2 + 1) * 16384;
    RD_AV(av1, A0, 1);
    MFMA_BLK(0, av0, bv0);
    PUB(0);
    RD_AV(av0, A1, 0);
    RD_BV(bv1, B1);
    MFMA_BLK(1, av1, bv0);
    RD_AV(av1, A1, 1);
    MFMA_BLK(0, av0, bv1);
    MFMA_BLK(1, av1, bv1);
  }

  // ---- epilogue: per-wave LDS transpose -> full-line NT stores.
  //      R20/R21 evidence: NT protects L3 residency of x/qw for the next
  //      replay's quant pass (total 425 vs 447), but 64B quarter-wave segments
  //      amplified writes 358->510MB. Transpose makes each quarter-wave write
  //      256B contiguous -> full 128B lines, no amplification. ----
  __builtin_amdgcn_s_barrier();   // all waves done reading As/Bs
  {
    float* ws = (float*)(lds + (size_t)wave * 4352);  // 16 rows x 68 f32 (padded)
    const int orow = (lane >> 4) * 4;
    const int rr = lane >> 2;          // read row 0..15
    const int cb = (lane & 3) * 16;    // read col base
    float sw_[4];
#pragma unroll
    for (int n = 0; n < 4; ++n) sw_[n] = swc[col0 + wn * 64 + n * 16 + fr];
#pragma unroll
    for (int mi = 0; mi < 8; ++mi) {
      const size_t rbase = row0 + wm * 128 + mi * 16;
      const f32x4 sx4 = *(const f32x4*)(sx + rbase + orow);
#pragma unroll
      for (int n = 0; n < 4; ++n)
#pragma unroll
        for (int v = 0; v < 4; ++v)
          ws[(orow + v) * 68 + n * 16 + fr] = (float)acc[mi][n][v] * sx4[v] * sw_[n];
      asm volatile("s_waitcnt lgkmcnt(0)" ::: "memory");
#pragma unroll
      for (int k = 0; k < 4; ++k) {
        f32x4 t = *(const f32x4*)&ws[rr * 68 + cb + 4 * k];
        __builtin_nontemporal_store(
            t, (f32x4*)&C[(rbase + rr) * N_DIM + col0 + wn * 64 + cb + 4 * k]);
      }
    }
  }
}

// ---------- fallback (only if d_ws too small): naive fused ----------
__global__ __launch_bounds__(256) void fallback_kernel(const float* __restrict__ x,
                                                       const int* __restrict__ qw,
                                                       const float* __restrict__ sc,
                                                       const float* __restrict__ zp,
                                                       float* __restrict__ out) {
  __shared__ float xs[K_DIM];
  const int m = blockIdx.y;
  const int n = blockIdx.x * 256 + threadIdx.x;
  for (int i = threadIdx.x; i < K_DIM; i += 256) xs[i] = x[(size_t)m * K_DIM + i];
  __syncthreads();
  float acc = 0.f;
  const int* wrow = qw + (size_t)n * (K_DIM / 2);
  for (int g = 0; g < NGROUP; ++g) {
    float s = sc[n * NGROUP + g];
    float z = zp[n * NGROUP + g];
    float partial = 0.f;
    for (int p = 0; p < 64; ++p) {
      int q = wrow[g * 64 + p];
      partial += xs[g * 128 + 2 * p]     * ((float)(q & 15) - z);
      partial += xs[g * 128 + 2 * p + 1] * ((float)((q >> 4) & 15) - z);
    }
    acc = fmaf(partial, s, acc);
  }
  out[(size_t)m * N_DIM + n] = acc;
}

extern "C" void kernel_launch(void* const* d_in, const int* in_sizes, int n_in,
                              void* d_out, int out_size, void* d_ws, size_t ws_size,
                              hipStream_t stream) {
  const float* x  = (const float*)d_in[0];
  const int*   qw = (const int*)d_in[1];
  const float* sc = (const float*)d_in[2];
  const float* zp = (const float*)d_in[3];
  float* out = (float*)d_out;

  const size_t xq_bytes = (size_t)M_DIM * K_DIM;        // 33,554,432
  const size_t wq_bytes = (size_t)N_DIM * K_DIM;        // 45,088,768
  const size_t sx_bytes = (size_t)M_DIM * 4;
  const size_t sw_bytes = (size_t)N_DIM * 4;

  if (ws_size >= xq_bytes + wq_bytes + sx_bytes + sw_bytes) {
    int8_t* xq = (int8_t*)d_ws;
    int8_t* wq = (int8_t*)d_ws + xq_bytes;
    float* sx  = (float*)((char*)d_ws + xq_bytes + wq_bytes);
    float* swc = (float*)((char*)d_ws + xq_bytes + wq_bytes + sx_bytes);
    quant_fused_kernel<<<dim3(M_DIM + N_DIM / 4), 256, 0, stream>>>(
        x, xq, sx, qw, sc, zp, wq, swc);
    dim3 grid((M_DIM / BM) * (N_DIM / BN));  // 32*43 = 1376
    gemm_i8_kernel<<<grid, dim3(512), 131072, stream>>>(xq, wq, sx, swc, out);
  } else {
    dim3 grid(N_DIM / 256, M_DIM);
    fallback_kernel<<<grid, 256, 0, stream>>>(x, qw, sc, zp, out);
  }
}

// Round 23
// 397.304 us; speedup vs baseline: 2.0060x; 2.0060x over previous
//
#include <hip/hip_runtime.h>
#include <hip/hip_bf16.h>
#include <stdint.h>

// Problem constants: B=4, S=2048, IN=4096, OUT=11008
#define M_DIM 8192   // B*S
#define N_DIM 11008  // OUT
#define K_DIM 4096   // IN
#define NGROUP 32    // K_DIM/128

#define BM 256
#define BN 256
#define BK 128
#define NT (K_DIM / BK)  // 32 K-tiles

typedef __attribute__((ext_vector_type(4))) int i32x4;
typedef __attribute__((ext_vector_type(4))) float f32x4;

static_assert(M_DIM % BM == 0 && N_DIM % BN == 0 && K_DIM % BK == 0, "tiling");

// ---------- fused prepass: blocks [0,8192) quantize x rows; [8192,10944) quantize W rows ----------
__global__ __launch_bounds__(256) void quant_fused_kernel(const float* __restrict__ x,
                                                          int8_t* __restrict__ xq,
                                                          float* __restrict__ sx,
                                                          const int* __restrict__ qw,
                                                          const float* __restrict__ sc,
                                                          const float* __restrict__ zp,
                                                          int8_t* __restrict__ wq,
                                                          float* __restrict__ swc) {
  __shared__ float red[4];
  __shared__ float sfin;
  const int tid = threadIdx.x;

  if (blockIdx.x < M_DIM) {
    // ---- x row -> i8, per-row scale ----
    const int m = blockIdx.x;
    const float* xr = x + (size_t)m * K_DIM;
    float4 v[4];
    float mx = 0.f;
#pragma unroll
    for (int i = 0; i < 4; ++i) {
      v[i] = *(const float4*)(xr + tid * 16 + i * 4);
      mx = fmaxf(mx, fmaxf(fmaxf(fabsf(v[i].x), fabsf(v[i].y)),
                           fmaxf(fabsf(v[i].z), fabsf(v[i].w))));
    }
#pragma unroll
    for (int off = 32; off; off >>= 1) mx = fmaxf(mx, __shfl_xor(mx, off));
    if ((tid & 63) == 0) red[tid >> 6] = mx;
    __syncthreads();
    if (tid == 0) {
      float t = fmaxf(fmaxf(red[0], red[1]), fmaxf(red[2], red[3]));
      t = fmaxf(t, 1e-20f);
      sfin = t;
      sx[m] = t * (1.0f / 127.0f);
    }
    __syncthreads();
    const float inv = 127.0f / sfin;
    int o[4];
#pragma unroll
    for (int i = 0; i < 4; ++i) {
      int q0 = (int)rintf(v[i].x * inv), q1 = (int)rintf(v[i].y * inv);
      int q2 = (int)rintf(v[i].z * inv), q3 = (int)rintf(v[i].w * inv);
      o[i] = (q0 & 0xff) | ((q1 & 0xff) << 8) | ((q2 & 0xff) << 16) | (q3 << 24);
    }
    *(int4*)(xq + (size_t)m * K_DIM + tid * 16) = make_int4(o[0], o[1], o[2], o[3]);
  } else {
    // ---- W row -> i8, per-output-row scale; single global read (row held in regs) ----
    const int o = (blockIdx.x - M_DIM) * 4 + (tid >> 6);
    const int lane = tid & 63;
    const int* row = qw + (size_t)o * 2048;
    const float* srow = sc + o * NGROUP;
    const float* zrow = zp + o * NGROUP;
    int q[32];
    float mx = 0.f;
#pragma unroll
    for (int i = 0; i < 32; ++i) {
      q[i] = row[i * 64 + lane];
      float s = srow[i], z = zrow[i];
      float lo = ((float)(q[i] & 15) - z) * s;
      float hi = ((float)((q[i] >> 4) & 15) - z) * s;
      mx = fmaxf(mx, fmaxf(fabsf(lo), fabsf(hi)));
    }
#pragma unroll
    for (int off = 32; off; off >>= 1) mx = fmaxf(mx, __shfl_xor(mx, off));
    mx = fmaxf(mx, 1e-20f);
    if (lane == 0) swc[o] = mx * (1.0f / 127.0f);
    const float inv = 127.0f / mx;
    short* out = (short*)(wq + (size_t)o * K_DIM);
#pragma unroll
    for (int i = 0; i < 32; ++i) {
      float s = srow[i], z = zrow[i];
      int rlo = (int)rintf(((float)(q[i] & 15) - z) * s * inv);
      int rhi = (int)rintf(((float)((q[i] >> 4) & 15) - z) * s * inv);
      out[i * 64 + lane] = (short)((rlo & 0xff) | (rhi << 8));
    }
  }
}

// ---------- 256x256 i8 GEMM, R9 schedule, BK=128, 2D XCD supertile,
//            NT FULL-LINE epilogue (fixed lane->col map) ----------
__device__ __forceinline__ void gload_lds16(const void* g, void* l) {
  __builtin_amdgcn_global_load_lds((__attribute__((address_space(1))) void*)g,
                                   (__attribute__((address_space(3))) void*)l,
                                   16, 0, 0);
}

// Stage one k-half panel [256 rows][64 i8] (16KB), 2 gload_lds per thread.
__device__ __forceinline__ void stage2(const int8_t* s0, const int8_t* s1,
                                       int8_t* panel, int wave, int koff) {
  gload_lds16(s0 + koff, panel + wave * 1024);
  gload_lds16(s1 + koff, panel + 8192 + wave * 1024);
}

#define VMC(N) asm volatile("s_waitcnt vmcnt(" #N ")" ::: "memory")
#define PUB(N) { VMC(N); __builtin_amdgcn_s_barrier(); }

// Fragment reads (i8: 16B = 16 elems along K per lane).
#define RD_AV(DST, P, MH)                                                    \
  _Pragma("unroll") for (int m_ = 0; m_ < 4; ++m_)                           \
    DST[m_] = *(const i32x4*)((P) + abase + ((MH)*4 + m_) * 1024);
#define RD_BV(DST, P)                                                        \
  _Pragma("unroll") for (int n_ = 0; n_ < 4; ++n_)                           \
    DST[n_] = *(const i32x4*)((P) + bbase + n_ * 1024);

#define MFMA_BLK(MH, AV, BV)                                                 \
  {                                                                          \
    __builtin_amdgcn_s_setprio(1);                                           \
    _Pragma("unroll") for (int m_ = 0; m_ < 4; ++m_)                         \
      _Pragma("unroll") for (int n_ = 0; n_ < 4; ++n_)                       \
        acc[(MH)*4 + m_][n_] = __builtin_amdgcn_mfma_i32_16x16x64_i8(        \
            AV[m_], BV[n_], acc[(MH)*4 + m_][n_], 0, 0, 0);                  \
    __builtin_amdgcn_s_setprio(0);                                           \
  }

__global__ __launch_bounds__(512, 2) void gemm_i8_kernel(const int8_t* __restrict__ A,
                                                         const int8_t* __restrict__ B,
                                                         const float* __restrict__ sx,
                                                         const float* __restrict__ swc,
                                                         float* __restrict__ C) {
  extern __shared__ int8_t lds[];
  int8_t* As = lds;            // [2 buf][2 kh][256*64]  = 64KB
  int8_t* Bs = lds + 65536;    // same                   = 64KB

  const int tid  = threadIdx.x;
  const int wave = tid >> 6;
  const int lane = tid & 63;
  const int wm = wave >> 2;   // 0..1 -> 128-row slab
  const int wn = wave & 3;    // 0..3 -> 64-col slab
  const int fr = lane & 15;
  const int cp = (lane >> 4) ^ ((fr >> 1) & 3);  // swizzled physical 16B-block

  // 2D XCD supertile (bijective, R20-verified: FETCH 759->278 MB)
  const int wg  = blockIdx.x;
  const int xcd = wg & 7;
  const int j   = wg >> 3;          // 0..171
  const int bm  = xcd * 4 + (j & 3);
  const int bn  = j >> 2;           // 0..42
  const size_t row0 = (size_t)bm * BM;
  const size_t col0 = (size_t)bn * BN;

  const int8_t* Ab = A + row0 * K_DIM;
  const int8_t* Bb = B + col0 * K_DIM;

  // per-lane staging sources (swizzle baked into global col, rule #21)
  const int cl = (tid & 3) ^ ((tid >> 3) & 3);
  const int r0 = tid >> 2;
  const int8_t* asrc0 = Ab + (size_t)r0 * K_DIM + cl * 16;
  const int8_t* asrc1 = Ab + (size_t)(r0 + 128) * K_DIM + cl * 16;
  const int8_t* bsrc0 = Bb + (size_t)r0 * K_DIM + cl * 16;
  const int8_t* bsrc1 = Bb + (size_t)(r0 + 128) * K_DIM + cl * 16;

  // fragment LDS byte offsets (panel-local); frag mf at abase + mf*1024
  const int abase = (wm * 128 + fr) * 64 + cp * 16;
  const int bbase = (wn * 64 + fr) * 64 + cp * 16;

  i32x4 acc[8][4];
#pragma unroll
  for (int i = 0; i < 8; ++i)
#pragma unroll
    for (int j2 = 0; j2 < 4; ++j2) acc[i][j2] = (i32x4){0, 0, 0, 0};

  i32x4 av0[4], av1[4], bv0[4], bv1[4];

  // ---- prologue: stage tile 0 fully; pre-read P1's fragments ----
  stage2(asrc0, asrc1, As + 0 * 16384, wave, 0);
  stage2(bsrc0, bsrc1, Bs + 0 * 16384, wave, 0);
  stage2(asrc0, asrc1, As + 1 * 16384, wave, 64);
  stage2(bsrc0, bsrc1, Bs + 1 * 16384, wave, 64);
  VMC(4);
  __builtin_amdgcn_s_barrier();
  RD_AV(av0, As + 0 * 16384, 0);
  RD_BV(bv0, Bs + 0 * 16384);

  // ---- main loop: R9 schedule, 4 phases/K-tile, publishes at P1/P3 ----
  for (int T = 0; T < NT - 1; ++T) {
    const int buf = T & 1, nb = buf ^ 1;
    int8_t* A0 = As + (buf * 2 + 0) * 16384;
    int8_t* A1 = As + (buf * 2 + 1) * 16384;
    int8_t* B1 = Bs + (buf * 2 + 1) * 16384;
    int8_t* nA0 = As + (nb * 2 + 0) * 16384;
    int8_t* nA1 = As + (nb * 2 + 1) * 16384;
    int8_t* nB0 = Bs + (nb * 2 + 0) * 16384;
    int8_t* nB1 = Bs + (nb * 2 + 1) * 16384;
    const int k0 = (T + 1) * 128;     // prefetch col offset (i8 elems)

    // P1: MFMA(kh0,mh0); pre-read av1<-A0.mh1; stage nA0; PUBLISH kh1
    RD_AV(av1, A0, 1);
    stage2(asrc0, asrc1, nA0, wave, k0);
    MFMA_BLK(0, av0, bv0);
    PUB(2);
    // P2: MFMA(kh0,mh1); pre-read av0<-A1.mh0, bv1<-B1; stage nB0
    RD_AV(av0, A1, 0);
    RD_BV(bv1, B1);
    stage2(bsrc0, bsrc1, nB0, wave, k0);
    MFMA_BLK(1, av1, bv0);
    // P3: MFMA(kh1,mh0); pre-read av1<-A1.mh1; stage nA1; PUBLISH next kh0
    RD_AV(av1, A1, 1);
    stage2(asrc0, asrc1, nA1, wave, k0 + 64);
    MFMA_BLK(0, av0, bv1);
    PUB(2);
    // P4: MFMA(kh1,mh1); pre-read next P1 frags from nA0,nB0; stage nB1
    RD_AV(av0, nA0, 0);
    RD_BV(bv0, nB0);
    stage2(bsrc0, bsrc1, nB1, wave, k0 + 64);
    MFMA_BLK(1, av1, bv1);
  }
  // ---- last tile: no staging; drain remaining at P1-end ----
  {
    const int buf = (NT - 1) & 1;
    int8_t* A0 = As + (buf * 2 + 0) * 16384;
    int8_t* A1 = As + (buf * 2 + 1) * 16384;
    int8_t* B1 = Bs + (buf * 2 + 1) * 16384;
    RD_AV(av1, A0, 1);
    MFMA_BLK(0, av0, bv0);
    PUB(0);
    RD_AV(av0, A1, 0);
    RD_BV(bv1, B1);
    MFMA_BLK(1, av1, bv0);
    RD_AV(av1, A1, 1);
    MFMA_BLK(0, av0, bv1);
    MFMA_BLK(1, av1, bv1);
  }

  // ---- epilogue: per-wave LDS transpose -> NT stores of FULL cache lines.
  //      R22 bug was cb=(lane&3)*16 (16B chunks at 64B stride -> partial-line NT,
  //      930MB). Fix: row=t*4+(lane>>4), col=(lane&15)*4 -> 16 lanes write 256B
  //      contiguous per row, 4 rows/instr -> whole 128B lines, no amplification.
  //      NT keeps the 360MB C-stream out of L2/L3 so x/qw stay L3-resident for
  //      the next replay's quant pass (R20/R21: quant 24 vs 62 us). ----
  __builtin_amdgcn_s_barrier();   // all waves done reading As/Bs
  {
    float* ws = (float*)lds + (size_t)wave * 1088;  // 16 rows x 68 f32 (padded)
    const int orow = (lane >> 4) * 4;
    const int hi = lane >> 4;          // 0..3
    const int fcol = (lane & 15) * 4;  // read col base (contiguous quads)
    float sw_[4];
#pragma unroll
    for (int n = 0; n < 4; ++n) sw_[n] = swc[col0 + wn * 64 + n * 16 + fr];
#pragma unroll
    for (int mi = 0; mi < 8; ++mi) {
      const size_t rbase = row0 + wm * 128 + mi * 16;
      const f32x4 sx4 = *(const f32x4*)(sx + rbase + orow);
#pragma unroll
      for (int n = 0; n < 4; ++n)
#pragma unroll
        for (int v = 0; v < 4; ++v)
          ws[(orow + v) * 68 + n * 16 + fr] = (float)acc[mi][n][v] * sx4[v] * sw_[n];
      asm volatile("s_waitcnt lgkmcnt(0)" ::: "memory");
#pragma unroll
      for (int t = 0; t < 4; ++t) {
        f32x4 tv = *(const f32x4*)&ws[(t * 4 + hi) * 68 + fcol];
        __builtin_nontemporal_store(
            tv, (f32x4*)&C[(rbase + t * 4 + hi) * N_DIM + col0 + wn * 64 + fcol]);
      }
      asm volatile("s_waitcnt lgkmcnt(0)" ::: "memory");  // reads done before next mi overwrites
    }
  }
}

// ---------- fallback (only if d_ws too small): naive fused ----------
__global__ __launch_bounds__(256) void fallback_kernel(const float* __restrict__ x,
                                                       const int* __restrict__ qw,
                                                       const float* __restrict__ sc,
                                                       const float* __restrict__ zp,
                                                       float* __restrict__ out) {
  __shared__ float xs[K_DIM];
  const int m = blockIdx.y;
  const int n = blockIdx.x * 256 + threadIdx.x;
  for (int i = threadIdx.x; i < K_DIM; i += 256) xs[i] = x[(size_t)m * K_DIM + i];
  __syncthreads();
  float acc = 0.f;
  const int* wrow = qw + (size_t)n * (K_DIM / 2);
  for (int g = 0; g < NGROUP; ++g) {
    float s = sc[n * NGROUP + g];
    float z = zp[n * NGROUP + g];
    float partial = 0.f;
    for (int p = 0; p < 64; ++p) {
      int q = wrow[g * 64 + p];
      partial += xs[g * 128 + 2 * p]     * ((float)(q & 15) - z);
      partial += xs[g * 128 + 2 * p + 1] * ((float)((q >> 4) & 15) - z);
    }
    acc = fmaf(partial, s, acc);
  }
  out[(size_t)m * N_DIM + n] = acc;
}

extern "C" void kernel_launch(void* const* d_in, const int* in_sizes, int n_in,
                              void* d_out, int out_size, void* d_ws, size_t ws_size,
                              hipStream_t stream) {
  const float* x  = (const float*)d_in[0];
  const int*   qw = (const int*)d_in[1];
  const float* sc = (const float*)d_in[2];
  const float* zp = (const float*)d_in[3];
  float* out = (float*)d_out;

  const size_t xq_bytes = (size_t)M_DIM * K_DIM;        // 33,554,432
  const size_t wq_bytes = (size_t)N_DIM * K_DIM;        // 45,088,768
  const size_t sx_bytes = (size_t)M_DIM * 4;
  const size_t sw_bytes = (size_t)N_DIM * 4;

  if (ws_size >= xq_bytes + wq_bytes + sx_bytes + sw_bytes) {
    int8_t* xq = (int8_t*)d_ws;
    int8_t* wq = (int8_t*)d_ws + xq_bytes;
    float* sx  = (float*)((char*)d_ws + xq_bytes + wq_bytes);
    float* swc = (float*)((char*)d_ws + xq_bytes + wq_bytes + sx_bytes);
    quant_fused_kernel<<<dim3(M_DIM + N_DIM / 4), 256, 0, stream>>>(
        x, xq, sx, qw, sc, zp, wq, swc);
    dim3 grid((M_DIM / BM) * (N_DIM / BN));  // 32*43 = 1376
    gemm_i8_kernel<<<grid, dim3(512), 131072, stream>>>(xq, wq, sx, swc, out);
  } else {
    dim3 grid(N_DIM / 256, M_DIM);
    fallback_kernel<<<grid, 256, 0, stream>>>(x, qw, sc, zp, out);
  }
}